// Round 5
// baseline (182.758 us; speedup 1.0000x reference)
//
#include <hip/hip_runtime.h>
#include <stdint.h>

typedef unsigned long long u64;
typedef unsigned int u32;
typedef unsigned char u8;

#define NB 8
#define NA 76725
#define NC 80
#define NCH 84
#define PRE_K 200
#define MAXPC 100
#define MAXDET 100
#define F4_PER_IMG (NA * 21u)   // 1,611,225 float4 per image

#define T0 0.93f                // exact gate: sigmoid > 0.93
#define XCUT 2.58f              // raw-logit prefilter (logit(0.93)=2.5867)
#define BLKX 256                // scan blocks per image
#define SPAN (BLKX * 256u)      // 65536 float4 per grid step
#define NSTEP 24                // 24*SPAN = 1,572,864 <= F4_PER_IMG
#define LCAP 24                 // per-block per-class LDS list cap
#define SEG 1920                // per-block segment capacity (80*24)
#define CROW 128                // counts row stride in bytes
#define CAP2 512                // k_nms sort size
#define CAPF 1024               // k_final sort size

// ---------- helpers ----------

__device__ __forceinline__ float sigmoid_ref(float x) {
    // match jax.nn.sigmoid = 1/(1+exp(-x)) in fp32 (no fast-math approx)
    return 1.0f / (1.0f + expf(-x));
}

// Decode one box exactly like the reference (fp32 ops, no fma contraction;
// anchor dims in double like the python host math, then cast to f32).
__device__ void decode_box(float4 d, int a, float4* box, float* areaOut) {
    int lvl, off, fw, stride;
    if (a < 57600)      { lvl = 0; off = 0;     fw = 80; stride = 8;   }
    else if (a < 72000) { lvl = 1; off = 57600; fw = 40; stride = 16;  }
    else if (a < 75600) { lvl = 2; off = 72000; fw = 20; stride = 32;  }
    else if (a < 76500) { lvl = 3; off = 75600; fw = 10; stride = 64;  }
    else                { lvl = 4; off = 76500; fw = 5;  stride = 128; }
    int idx  = a - off;
    int k    = idx % 9;
    int cell = idx / 9;
    int row = cell / fw, col = cell - row * fw;
    float cx = __fmul_rn((float)col + 0.5f, (float)stride);
    float cy = __fmul_rn((float)row + 0.5f, (float)stride);
    int ri = k / 3, si = k - ri * 3;
    double r    = (ri == 0) ? 0.5 : ((ri == 1) ? 1.0 : 2.0);
    double side = (double)(32 << lvl);
    double area = side * side;
    double h = sqrt(area / r);
    double w = area / h;
    double s = exp2((double)si / 3.0);
    float aw = (float)(s * w);
    float ah = (float)(s * h);
    float b0 = __fmul_rn(d.x, 0.1f);
    float b1 = __fmul_rn(d.y, 0.1f);
    float b2 = __fmul_rn(d.z, 0.2f);
    float b3 = __fmul_rn(d.w, 0.2f);
    float ux = __fadd_rn(__fmul_rn(b0, aw), cx);
    float uy = __fadd_rn(__fmul_rn(b1, ah), cy);
    float wx = __fmul_rn(expf(b2), aw);
    float wy = __fmul_rn(expf(b3), ah);
    float hx = __fmul_rn(wx, 0.5f);
    float hy = __fmul_rn(wy, 0.5f);
    float x1 = __fsub_rn(ux, hx), y1 = __fsub_rn(uy, hy);
    float x2 = __fadd_rn(ux, hx), y2 = __fadd_rn(uy, hy);
    *box = make_float4(x1, y1, x2, y2);
    *areaOut = __fmul_rn(__fsub_rn(x2, x1), __fsub_rn(y2, y1));
}

// descending bitonic sort of n (power of 2) u64 keys in LDS
__device__ __forceinline__ void bitonic_desc(u64* keys, u32 n) {
    for (u32 k = 2; k <= n; k <<= 1) {
        for (u32 j = k >> 1; j > 0; j >>= 1) {
            for (u32 i = threadIdx.x; i < n; i += blockDim.x) {
                u32 ixj = i ^ j;
                if (ixj > i) {
                    u64 x = keys[i], y = keys[ixj];
                    if (((i & k) == 0u) ? (x < y) : (x > y)) {
                        keys[i] = y; keys[ixj] = x;
                    }
                }
            }
            __syncthreads();
        }
    }
}

// ---------- kernel 1: streaming scan, block-private class-grouped output ----------

__device__ __forceinline__ void scan4(float4 v, u32 idx,
                                      u32* lhist, u64 (*llist)[LCAP]) {
    u32 a  = idx / 21u;
    u32 c4 = idx - a * 21u;
    if (c4 == 0u) return;                        // box channels
    float m = fmaxf(fmaxf(v.x, v.y), fmaxf(v.z, v.w));
    if (m <= XCUT) return;
    u32 cb = c4 * 4u - 4u;
    float vv[4] = {v.x, v.y, v.z, v.w};
#pragma unroll
    for (int q = 0; q < 4; ++q) {
        if (vv[q] > XCUT) {
            float sig = sigmoid_ref(vv[q]);
            if (sig > T0) {
                u32 c = cb + (u32)q;
                u64 key = ((u64)__float_as_uint(sig) << 32) | (u64)(~a);
                u32 p = atomicAdd(&lhist[c], 1u);
                if (p < LCAP) llist[c][p] = key;
                // overflow (never in practice): count records it; k_nms repairs
            }
        }
    }
}

__global__ __launch_bounds__(256, 4) void k_scan(const float4* __restrict__ p4,
                                                 u64* __restrict__ seg,
                                                 u8* __restrict__ counts) {
    __shared__ u32 lhist[NC];
    __shared__ u64 llist[NC][LCAP];
    __shared__ u32 hs[128];
    u32 b = blockIdx.y, x = blockIdx.x;
    for (u32 c = threadIdx.x; c < NC; c += 256u) lhist[c] = 0u;
    __syncthreads();

    const float4* base = p4 + (u64)b * F4_PER_IMG;
    u32 i0 = x * 256u + threadIdx.x;
#pragma unroll 1
    for (int s = 0; s < NSTEP; s += 4) {
        u32 ia = i0 + (u32)s * SPAN;
        float4 v0 = base[ia];
        float4 v1 = base[ia + SPAN];
        float4 v2 = base[ia + 2u * SPAN];
        float4 v3 = base[ia + 3u * SPAN];
        scan4(v0, ia,            lhist, llist);
        scan4(v1, ia + SPAN,     lhist, llist);
        scan4(v2, ia + 2u*SPAN,  lhist, llist);
        scan4(v3, ia + 3u*SPAN,  lhist, llist);
    }
    {
        u32 it = i0 + (u32)NSTEP * SPAN;
        if (it < F4_PER_IMG) scan4(base[it], it, lhist, llist);
    }
    __syncthreads();

    // inclusive prefix (Hillis-Steele) over clamped counts, 128-padded
    if (threadIdx.x < 128u)
        hs[threadIdx.x] = (threadIdx.x < NC)
                        ? (lhist[threadIdx.x] < LCAP ? lhist[threadIdx.x] : (u32)LCAP)
                        : 0u;
    __syncthreads();
    for (u32 d = 1; d < 128u; d <<= 1) {
        u32 v = 0;
        if (threadIdx.x < 128u && threadIdx.x >= d) v = hs[threadIdx.x - d];
        __syncthreads();
        if (threadIdx.x < 128u) hs[threadIdx.x] += v;
        __syncthreads();
    }

    // flush: class-grouped copy to private segment + count row (no atomics)
    if (threadIdx.x < NC) {
        u32 c = threadIdx.x;
        u32 n = lhist[c];
        u32 m = n < LCAP ? n : (u32)LCAP;
        u32 dst = hs[c] - m;
        u64* o = seg + (u64)(b * BLKX + x) * SEG + dst;
        for (u32 j = 0; j < m; ++j) o[j] = llist[c][j];
        counts[(b * BLKX + x) * CROW + c] = (u8)(n < 255u ? n : 255u);
    }
}

// ---------- kernel 2: gather + gate + (rare) exact repair + sort + NMS ----------

__global__ __launch_bounds__(512) void k_nms(const float* __restrict__ pred,
                                             const u64* __restrict__ seg,
                                             const u8* __restrict__ counts,
                                             float* __restrict__ sc2,
                                             float* __restrict__ bb2) {
    int bc = blockIdx.x;
    int b = bc / NC, c = bc % NC;
    __shared__ u64 keys[CAP2];
    __shared__ u32 gc[BLKX];
    __shared__ u32 srcoff[BLKX];
    __shared__ u32 gflag;
    __shared__ u32 gtot;
    __shared__ float4 box[PRE_K];
    __shared__ float area[PRE_K];
    __shared__ u32 supp[PRE_K][7];
    __shared__ u32 keepw[7];
    __shared__ u64 red[512];

    if (threadIdx.x == 0) gflag = 0u;
    __syncthreads();

    u32 n_c = 0;
    if (threadIdx.x < BLKX) {
        int blk = threadIdx.x;
        const u8* crow = counts + (u64)(b * BLKX + blk) * CROW;
        u32 cp = 0;
        for (int cc = 0; cc < NC; ++cc) {
            u32 nv = crow[cc];
            u32 mv = nv < LCAP ? nv : (u32)LCAP;
            if (cc < c) cp += mv;
            if (cc == c) { n_c = mv; if (nv > (u32)LCAP) atomicOr(&gflag, 1u); }
        }
        gc[threadIdx.x] = n_c;
        srcoff[threadIdx.x] = cp;
    }
    __syncthreads();
    for (u32 d = 1; d < BLKX; d <<= 1) {
        u32 v = 0;
        if (threadIdx.x < BLKX && threadIdx.x >= d) v = gc[threadIdx.x - d];
        __syncthreads();
        if (threadIdx.x < BLKX) gc[threadIdx.x] += v;
        __syncthreads();
    }
    if (threadIdx.x == 0) gtot = gc[BLKX - 1];
    __syncthreads();
    u32 total = gtot;
    bool repaired = (gflag != 0u) || (total < (u32)PRE_K) || (total > (u32)CAP2);

    if (!repaired) {
        if (threadIdx.x < BLKX) {
            u32 dst = gc[threadIdx.x] - n_c;
            const u64* src = seg + (u64)(b * BLKX + threadIdx.x) * SEG + srcoff[threadIdx.x];
            for (u32 j = 0; j < n_c; ++j) keys[dst + j] = src[j];
        }
        for (u32 i = threadIdx.x; i < CAP2; i += blockDim.x)
            if (i >= total) keys[i] = 0ull;
        __syncthreads();
        bitonic_desc(keys, CAP2);
    } else {
        // exact argmax-extraction top-200 (never taken for this input; exact)
        u64 cur = ~0ull;
        for (int k = 0; k < PRE_K; ++k) {
            u64 loc = 0;
            for (int a = threadIdx.x; a < NA; a += blockDim.x) {
                float xx = pred[((long)b * NA + a) * NCH + 4 + c];
                float sg = sigmoid_ref(xx);
                u64 key  = ((u64)__float_as_uint(sg) << 32) | (u64)(~(u32)a);
                if (key < cur && key > loc) loc = key;
            }
            red[threadIdx.x] = loc;
            __syncthreads();
            for (int s = 256; s > 0; s >>= 1) {
                if (threadIdx.x < (u32)s) {
                    if (red[threadIdx.x + s] > red[threadIdx.x])
                        red[threadIdx.x] = red[threadIdx.x + s];
                }
                __syncthreads();
            }
            cur = red[0];
            if (threadIdx.x == 0) keys[k] = cur;
            __syncthreads();
        }
        for (u32 i = PRE_K + threadIdx.x; i < CAP2; i += blockDim.x) keys[i] = 0ull;
        __syncthreads();
    }

    for (int i = threadIdx.x; i < PRE_K * 7; i += blockDim.x) supp[i / 7][i % 7] = 0u;
    if (threadIdx.x < 7) keepw[threadIdx.x] = 0u;
    __syncthreads();

    if (threadIdx.x < PRE_K) {
        int r   = threadIdx.x;
        u64 key = keys[r];
        float sig = __uint_as_float((u32)(key >> 32));
        int a = (int)(~(u32)key);
        float4 bx = make_float4(0.f, 0.f, 0.f, 0.f);
        float ar = 0.f;
        if (sig > 0.05f) {  // valid = sc > CONF_THR
            float4 dd = *(const float4*)(pred + ((long)b * NA + a) * NCH);
            decode_box(dd, a, &bx, &ar);
            atomicOr(&keepw[r >> 5], 1u << (r & 31));
        }
        box[r] = bx; area[r] = ar;
    }
    __syncthreads();

    // suppression bitmask: bit j set for pairs j>i with IoU>0.5
    for (int p = threadIdx.x; p < PRE_K * PRE_K; p += blockDim.x) {
        int i  = p / PRE_K;
        int jx = p - i * PRE_K;
        if (jx > i) {
            float4 bi = box[i], bj = box[jx];
            float ltx = fmaxf(bi.x, bj.x), lty = fmaxf(bi.y, bj.y);
            float rbx = fminf(bi.z, bj.z), rby = fminf(bi.w, bj.w);
            float wx = fmaxf(__fsub_rn(rbx, ltx), 0.f);
            float wy = fmaxf(__fsub_rn(rby, lty), 0.f);
            float inter = __fmul_rn(wx, wy);
            float den = __fadd_rn(__fsub_rn(__fadd_rn(area[i], area[jx]), inter), 1e-8f);
            float iou = __fdiv_rn(inter, den);
            if (iou > 0.5f) atomicOr(&supp[i][jx >> 5], 1u << (jx & 31));
        }
    }
    __syncthreads();

    // serial greedy sweep (matches fori_loop exactly)
    if (threadIdx.x == 0) {
        u32 kw[7];
#pragma unroll
        for (int w = 0; w < 7; ++w) kw[w] = keepw[w];
        for (int i = 0; i < PRE_K; ++i) {
            if ((kw[i >> 5] >> (i & 31)) & 1u) {
#pragma unroll
                for (int w = 0; w < 7; ++w) kw[w] &= ~supp[i][w];
            }
        }
#pragma unroll
        for (int w = 0; w < 7; ++w) keepw[w] = kw[w];
    }
    __syncthreads();

    // full write of per-class top-100 (zero-fill; no memset dependency)
    int kept = 0;
#pragma unroll
    for (int w = 0; w < 7; ++w) kept += __popc(keepw[w]);
    if (kept > MAXPC) kept = MAXPC;

    if (threadIdx.x >= (u32)kept && threadIdx.x < MAXPC) {
        int pos = threadIdx.x;
        sc2[bc * MAXPC + pos] = 0.f;
        float* o = bb2 + ((long)bc * MAXPC + pos) * 4;
        o[0] = 0.f; o[1] = 0.f; o[2] = 0.f; o[3] = 0.f;
    }
    if (threadIdx.x < PRE_K) {
        int r = threadIdx.x;
        if ((keepw[r >> 5] >> (r & 31)) & 1u) {
            int pos = 0;
            for (int w = 0; w < (r >> 5); ++w) pos += __popc(keepw[w]);
            pos += __popc(keepw[r >> 5] & ((1u << (r & 31)) - 1u));
            if (pos < MAXPC) {
                u64 key = keys[r];
                float sig = __uint_as_float((u32)(key >> 32));
                sc2[bc * MAXPC + pos] = sig;
                float4 bx = box[r];
                float* o = bb2 + ((long)bc * MAXPC + pos) * 4;
                o[0] = bx.x; o[1] = bx.y; o[2] = bx.z; o[3] = bx.w;
            }
        }
    }
}

// ---------- kernel 3: per-image final top-100 + full output write ----------

__global__ __launch_bounds__(1024) void k_final(const float* __restrict__ sc2,
                                                const float* __restrict__ bb2,
                                                float* __restrict__ out) {
    int b = blockIdx.x;
    __shared__ u32 hist[256];
    __shared__ u64 keys[CAPF];
    __shared__ u32 cnt_s;
    __shared__ int t_s;
    for (int i = threadIdx.x; i < 256; i += blockDim.x) hist[i] = 0u;
    if (threadIdx.x == 0) cnt_s = 0u;
    __syncthreads();

    const float* s_b = sc2 + b * (NC * MAXPC);
    for (int f = threadIdx.x; f < NC * MAXPC; f += blockDim.x) {
        float s = s_b[f];
        if (s > 0.f) {
            int bin = (int)(s * 256.f); if (bin > 255) bin = 255;
            atomicAdd(&hist[bin], 1u);
        }
    }
    __syncthreads();
    if (threadIdx.x == 0) {
        u32 cum = 0; int t = 0;
        for (int bin = 255; bin >= 0; --bin) {
            cum += hist[bin];
            if (cum >= (u32)MAXDET) { t = bin; break; }
        }
        t_s = t;
    }
    __syncthreads();
    int t = t_s;
    for (int f = threadIdx.x; f < NC * MAXPC; f += blockDim.x) {
        float s = s_b[f];
        if (s > 0.f) {
            int bin = (int)(s * 256.f); if (bin > 255) bin = 255;
            if (bin >= t) {
                u32 pos = atomicAdd(&cnt_s, 1u);
                if (pos < CAPF)
                    keys[pos] = ((u64)__float_as_uint(s) << 32) | (u64)(~(u32)f);
            }
        }
    }
    __syncthreads();
    u32 g = cnt_s; if (g > (u32)CAPF) g = CAPF;
    for (int i = threadIdx.x; i < CAPF; i += blockDim.x)
        if (i >= (int)g) keys[i] = 0ull;
    __syncthreads();

    bitonic_desc(keys, CAPF);

    if (threadIdx.x < MAXDET) {
        int r = threadIdx.x;
        u64 key = keys[r];
        u32 hi = (u32)(key >> 32);
        float s = 0.f, cf = 0.f;
        float bx0 = 0.f, bx1 = 0.f, bx2 = 0.f, bx3 = 0.f;
        if (hi != 0u) {
            s = __uint_as_float(hi);
            int f = (int)(~(u32)key);
            int c = f / MAXPC, jj = f - c * MAXPC;
            const float* bsrc = bb2 + ((long)(b * NC + c) * MAXPC + jj) * 4;
            bx0 = bsrc[0]; bx1 = bsrc[1]; bx2 = bsrc[2]; bx3 = bsrc[3];
            cf = (float)c;
        }
        float* ob = out + ((long)b * MAXDET + r) * 4;
        ob[0] = bx0; ob[1] = bx1; ob[2] = bx2; ob[3] = bx3;
        out[NB * MAXDET * 4 + b * MAXDET + r] = s;
        out[NB * MAXDET * 4 + NB * MAXDET + b * MAXDET + r] = cf;
    }
    __syncthreads();
    if (threadIdx.x == 0) {
        int nv = 0;
        for (int r = 0; r < MAXDET; ++r)
            if ((u32)(keys[r] >> 32) != 0u) ++nv;
        out[NB * MAXDET * 4 + 2 * NB * MAXDET + b] = (float)nv;
    }
}

// ---------- launcher ----------

extern "C" void kernel_launch(void* const* d_in, const int* in_sizes, int n_in,
                              void* d_out, int out_size, void* d_ws, size_t ws_size,
                              hipStream_t stream) {
    // inputs: images [8,640,640,3] (unused), predictions [8,76725,84]
    const float* pred = (const float*)d_in[1];
    if (n_in >= 2 && in_sizes[0] == NB * NA * NCH) pred = (const float*)d_in[0];

    char* ws = (char*)d_ws;
    const long NBLK = (long)NB * BLKX;                 // 2048
    u64* seg   = (u64*)ws;                             // 2048*1920*8 = 31,457,280 B
    char* p    = ws + NBLK * SEG * 8;
    u8* counts = (u8*)p;             p += NBLK * CROW; // 262,144 B
    float* sc2 = (float*)p;          p += (long)NB * NC * MAXPC * 4;   // 256,000 B
    float* bb2 = (float*)p;                            // 1,024,000 B

    k_scan <<<dim3(BLKX, NB), 256, 0, stream>>>((const float4*)pred, seg, counts);
    k_nms  <<<dim3(NB * NC),  512, 0, stream>>>(pred, seg, counts, sc2, bb2);
    k_final<<<dim3(NB),      1024, 0, stream>>>(sc2, bb2, (float*)d_out);
}

// Round 6
// 135.541 us; speedup vs baseline: 1.3484x; 1.3484x over previous
//
#include <hip/hip_runtime.h>
#include <stdint.h>

typedef unsigned long long u64;
typedef unsigned int u32;
typedef unsigned char u8;

#define NB 8
#define NA 76725
#define NC 80
#define NCH 84
#define PRE_K 200
#define MAXPC 100
#define MAXDET 100
#define F4_PER_IMG (NA * 21u)   // 1,611,225 float4 per image

#define T0 0.93f                // exact gate: sigmoid > 0.93
#define XCUT 2.58f              // raw-logit prefilter (logit(0.93)=2.5867)
#define BLKX 256                // scan blocks per image
#define SPAN (BLKX * 256u)      // 65536 float4 per grid step
#define NSTEP 24                // 24*SPAN = 1,572,864 <= F4_PER_IMG
#define LCAP 24                 // per-(block,class) slot cap (P(overflow)~0)
#define CAP2 512                // k_nms sort size
#define CAPF 1024               // k_final sort size

// ---------- helpers ----------

__device__ __forceinline__ float sigmoid_ref(float x) {
    // match jax.nn.sigmoid = 1/(1+exp(-x)) in fp32 (no fast-math approx)
    return 1.0f / (1.0f + expf(-x));
}

// Decode one box exactly like the reference (fp32 ops, no fma contraction;
// anchor dims in double like the python host math, then cast to f32).
__device__ void decode_box(float4 d, int a, float4* box, float* areaOut) {
    int lvl, off, fw, stride;
    if (a < 57600)      { lvl = 0; off = 0;     fw = 80; stride = 8;   }
    else if (a < 72000) { lvl = 1; off = 57600; fw = 40; stride = 16;  }
    else if (a < 75600) { lvl = 2; off = 72000; fw = 20; stride = 32;  }
    else if (a < 76500) { lvl = 3; off = 75600; fw = 10; stride = 64;  }
    else                { lvl = 4; off = 76500; fw = 5;  stride = 128; }
    int idx  = a - off;
    int k    = idx % 9;
    int cell = idx / 9;
    int row = cell / fw, col = cell - row * fw;
    float cx = __fmul_rn((float)col + 0.5f, (float)stride);
    float cy = __fmul_rn((float)row + 0.5f, (float)stride);
    int ri = k / 3, si = k - ri * 3;
    double r    = (ri == 0) ? 0.5 : ((ri == 1) ? 1.0 : 2.0);
    double side = (double)(32 << lvl);
    double area = side * side;
    double h = sqrt(area / r);
    double w = area / h;
    double s = exp2((double)si / 3.0);
    float aw = (float)(s * w);
    float ah = (float)(s * h);
    float b0 = __fmul_rn(d.x, 0.1f);
    float b1 = __fmul_rn(d.y, 0.1f);
    float b2 = __fmul_rn(d.z, 0.2f);
    float b3 = __fmul_rn(d.w, 0.2f);
    float ux = __fadd_rn(__fmul_rn(b0, aw), cx);
    float uy = __fadd_rn(__fmul_rn(b1, ah), cy);
    float wx = __fmul_rn(expf(b2), aw);
    float wy = __fmul_rn(expf(b3), ah);
    float hx = __fmul_rn(wx, 0.5f);
    float hy = __fmul_rn(wy, 0.5f);
    float x1 = __fsub_rn(ux, hx), y1 = __fsub_rn(uy, hy);
    float x2 = __fadd_rn(ux, hx), y2 = __fadd_rn(uy, hy);
    *box = make_float4(x1, y1, x2, y2);
    *areaOut = __fmul_rn(__fsub_rn(x2, x1), __fsub_rn(y2, y1));
}

// descending bitonic sort of n (power of 2) u64 keys in LDS
__device__ __forceinline__ void bitonic_desc(u64* keys, u32 n) {
    for (u32 k = 2; k <= n; k <<= 1) {
        for (u32 j = k >> 1; j > 0; j >>= 1) {
            for (u32 i = threadIdx.x; i < n; i += blockDim.x) {
                u32 ixj = i ^ j;
                if (ixj > i) {
                    u64 x = keys[i], y = keys[ixj];
                    if (((i & k) == 0u) ? (x < y) : (x > y)) {
                        keys[i] = y; keys[ixj] = x;
                    }
                }
            }
            __syncthreads();
        }
    }
}

// ---------- kernel 1: streaming scan, class-major flush (no global atomics) ----------

__device__ __forceinline__ void scan4(float4 v, u32 idx,
                                      u32* lhist, u64 (*llist)[LCAP]) {
    u32 a  = idx / 21u;
    u32 c4 = idx - a * 21u;
    if (c4 == 0u) return;                        // box channels
    float m = fmaxf(fmaxf(v.x, v.y), fmaxf(v.z, v.w));
    if (m <= XCUT) return;
    u32 cb = c4 * 4u - 4u;
    float vv[4] = {v.x, v.y, v.z, v.w};
#pragma unroll
    for (int q = 0; q < 4; ++q) {
        if (vv[q] > XCUT) {
            float sig = sigmoid_ref(vv[q]);
            if (sig > T0) {
                u32 c = cb + (u32)q;
                u64 key = ((u64)__float_as_uint(sig) << 32) | (u64)(~a);
                u32 p = atomicAdd(&lhist[c], 1u);
                if (p < LCAP) llist[c][p] = key;
                // overflow (never in practice): unclamped count triggers repair
            }
        }
    }
}

__global__ __launch_bounds__(256, 4) void k_scan(const float4* __restrict__ p4,
                                                 u64* __restrict__ seg,
                                                 u32* __restrict__ cntT) {
    __shared__ u32 lhist[NC];
    __shared__ u64 llist[NC][LCAP];
    u32 b = blockIdx.y, x = blockIdx.x;
    for (u32 c = threadIdx.x; c < NC; c += 256u) lhist[c] = 0u;
    __syncthreads();

    const float4* base = p4 + (u64)b * F4_PER_IMG;
    u32 i0 = x * 256u + threadIdx.x;
#pragma unroll 1
    for (int s = 0; s < NSTEP; s += 4) {
        u32 ia = i0 + (u32)s * SPAN;
        float4 v0 = base[ia];
        float4 v1 = base[ia + SPAN];
        float4 v2 = base[ia + 2u * SPAN];
        float4 v3 = base[ia + 3u * SPAN];
        scan4(v0, ia,            lhist, llist);
        scan4(v1, ia + SPAN,     lhist, llist);
        scan4(v2, ia + 2u*SPAN,  lhist, llist);
        scan4(v3, ia + 3u*SPAN,  lhist, llist);
    }
    {
        u32 it = i0 + (u32)NSTEP * SPAN;
        if (it < F4_PER_IMG) scan4(base[it], it, lhist, llist);
    }
    __syncthreads();

    // class-major flush: block x owns slot row [ (b*NC+c)*BLKX + x ] * LCAP
    if (threadIdx.x < NC) {
        u32 c = threadIdx.x;
        u32 n = lhist[c];
        u32 m = n < LCAP ? n : (u32)LCAP;
        u64* o = seg + ((u64)(b * NC + c) * BLKX + x) * LCAP;
        for (u32 j = 0; j < m; ++j) o[j] = llist[c][j];
        cntT[(b * NC + c) * BLKX + x] = n;
    }
}

// ---------- kernel 2: coalesced gather + gate + (rare) repair + sort + NMS ----------

__global__ __launch_bounds__(512) void k_nms(const float* __restrict__ pred,
                                             const u64* __restrict__ seg,
                                             const u32* __restrict__ cntT,
                                             float* __restrict__ sc2,
                                             float* __restrict__ bb2) {
    int bc = blockIdx.x;
    int b = bc / NC, c = bc % NC;
    __shared__ u64 keys[CAP2];
    __shared__ u32 gc[BLKX];
    __shared__ u32 gflag;
    __shared__ u32 gtot;
    __shared__ float4 box[PRE_K];
    __shared__ float area[PRE_K];
    __shared__ u32 supp[PRE_K][7];
    __shared__ u32 keepw[7];
    __shared__ u64 red[512];

    if (threadIdx.x == 0) gflag = 0u;
    __syncthreads();

    // coalesced: 256 consecutive u32 counts for this (b,c)
    u32 m_c = 0;
    if (threadIdx.x < BLKX) {
        u32 n = cntT[(u64)bc * BLKX + threadIdx.x];
        if (n > (u32)LCAP) atomicOr(&gflag, 1u);
        m_c = n < LCAP ? n : (u32)LCAP;
        gc[threadIdx.x] = m_c;
    }
    __syncthreads();
    for (u32 d = 1; d < BLKX; d <<= 1) {
        u32 v = 0;
        if (threadIdx.x < BLKX && threadIdx.x >= d) v = gc[threadIdx.x - d];
        __syncthreads();
        if (threadIdx.x < BLKX) gc[threadIdx.x] += v;
        __syncthreads();
    }
    if (threadIdx.x == 0) gtot = gc[BLKX - 1];
    __syncthreads();
    u32 total = gtot;
    bool repaired = (gflag != 0u) || (total < (u32)PRE_K) || (total > (u32)CAP2);

    if (!repaired) {
        if (threadIdx.x < BLKX) {
            u32 dst = gc[threadIdx.x] - m_c;
            const u64* src = seg + ((u64)bc * BLKX + threadIdx.x) * LCAP;
            for (u32 j = 0; j < m_c; ++j) keys[dst + j] = src[j];
        }
        for (u32 i = threadIdx.x; i < CAP2; i += blockDim.x)
            if (i >= total) keys[i] = 0ull;
        __syncthreads();
        bitonic_desc(keys, CAP2);
    } else {
        // exact argmax-extraction top-200 (never taken for this input; exact)
        u64 cur = ~0ull;
        for (int k = 0; k < PRE_K; ++k) {
            u64 loc = 0;
            for (int a = threadIdx.x; a < NA; a += blockDim.x) {
                float xx = pred[((long)b * NA + a) * NCH + 4 + c];
                float sg = sigmoid_ref(xx);
                u64 key  = ((u64)__float_as_uint(sg) << 32) | (u64)(~(u32)a);
                if (key < cur && key > loc) loc = key;
            }
            red[threadIdx.x] = loc;
            __syncthreads();
            for (int s = 256; s > 0; s >>= 1) {
                if (threadIdx.x < (u32)s) {
                    if (red[threadIdx.x + s] > red[threadIdx.x])
                        red[threadIdx.x] = red[threadIdx.x + s];
                }
                __syncthreads();
            }
            cur = red[0];
            if (threadIdx.x == 0) keys[k] = cur;
            __syncthreads();
        }
        for (u32 i = PRE_K + threadIdx.x; i < CAP2; i += blockDim.x) keys[i] = 0ull;
        __syncthreads();
    }

    for (int i = threadIdx.x; i < PRE_K * 7; i += blockDim.x) supp[i / 7][i % 7] = 0u;
    if (threadIdx.x < 7) keepw[threadIdx.x] = 0u;
    __syncthreads();

    if (threadIdx.x < PRE_K) {
        int r   = threadIdx.x;
        u64 key = keys[r];
        float sig = __uint_as_float((u32)(key >> 32));
        int a = (int)(~(u32)key);
        float4 bx = make_float4(0.f, 0.f, 0.f, 0.f);
        float ar = 0.f;
        if (sig > 0.05f) {  // valid = sc > CONF_THR
            float4 dd = *(const float4*)(pred + ((long)b * NA + a) * NCH);
            decode_box(dd, a, &bx, &ar);
            atomicOr(&keepw[r >> 5], 1u << (r & 31));
        }
        box[r] = bx; area[r] = ar;
    }
    __syncthreads();

    // suppression bitmask: bit j set for pairs j>i with IoU>0.5
    for (int p = threadIdx.x; p < PRE_K * PRE_K; p += blockDim.x) {
        int i  = p / PRE_K;
        int jx = p - i * PRE_K;
        if (jx > i) {
            float4 bi = box[i], bj = box[jx];
            float ltx = fmaxf(bi.x, bj.x), lty = fmaxf(bi.y, bj.y);
            float rbx = fminf(bi.z, bj.z), rby = fminf(bi.w, bj.w);
            float wx = fmaxf(__fsub_rn(rbx, ltx), 0.f);
            float wy = fmaxf(__fsub_rn(rby, lty), 0.f);
            float inter = __fmul_rn(wx, wy);
            float den = __fadd_rn(__fsub_rn(__fadd_rn(area[i], area[jx]), inter), 1e-8f);
            float iou = __fdiv_rn(inter, den);
            if (iou > 0.5f) atomicOr(&supp[i][jx >> 5], 1u << (jx & 31));
        }
    }
    __syncthreads();

    // serial greedy sweep (matches fori_loop exactly)
    if (threadIdx.x == 0) {
        u32 kw[7];
#pragma unroll
        for (int w = 0; w < 7; ++w) kw[w] = keepw[w];
        for (int i = 0; i < PRE_K; ++i) {
            if ((kw[i >> 5] >> (i & 31)) & 1u) {
#pragma unroll
                for (int w = 0; w < 7; ++w) kw[w] &= ~supp[i][w];
            }
        }
#pragma unroll
        for (int w = 0; w < 7; ++w) keepw[w] = kw[w];
    }
    __syncthreads();

    // full write of per-class top-100 (zero-fill; no memset dependency)
    int kept = 0;
#pragma unroll
    for (int w = 0; w < 7; ++w) kept += __popc(keepw[w]);
    if (kept > MAXPC) kept = MAXPC;

    if (threadIdx.x >= (u32)kept && threadIdx.x < MAXPC) {
        int pos = threadIdx.x;
        sc2[bc * MAXPC + pos] = 0.f;
        float* o = bb2 + ((long)bc * MAXPC + pos) * 4;
        o[0] = 0.f; o[1] = 0.f; o[2] = 0.f; o[3] = 0.f;
    }
    if (threadIdx.x < PRE_K) {
        int r = threadIdx.x;
        if ((keepw[r >> 5] >> (r & 31)) & 1u) {
            int pos = 0;
            for (int w = 0; w < (r >> 5); ++w) pos += __popc(keepw[w]);
            pos += __popc(keepw[r >> 5] & ((1u << (r & 31)) - 1u));
            if (pos < MAXPC) {
                u64 key = keys[r];
                float sig = __uint_as_float((u32)(key >> 32));
                sc2[bc * MAXPC + pos] = sig;
                float4 bx = box[r];
                float* o = bb2 + ((long)bc * MAXPC + pos) * 4;
                o[0] = bx.x; o[1] = bx.y; o[2] = bx.z; o[3] = bx.w;
            }
        }
    }
}

// ---------- kernel 3: per-image final top-100 + full output write ----------

__global__ __launch_bounds__(1024) void k_final(const float* __restrict__ sc2,
                                                const float* __restrict__ bb2,
                                                float* __restrict__ out) {
    int b = blockIdx.x;
    __shared__ u32 hist[256];
    __shared__ u64 keys[CAPF];
    __shared__ u32 cnt_s;
    __shared__ int t_s;
    for (int i = threadIdx.x; i < 256; i += blockDim.x) hist[i] = 0u;
    if (threadIdx.x == 0) cnt_s = 0u;
    __syncthreads();

    const float* s_b = sc2 + b * (NC * MAXPC);
    for (int f = threadIdx.x; f < NC * MAXPC; f += blockDim.x) {
        float s = s_b[f];
        if (s > 0.f) {
            int bin = (int)(s * 256.f); if (bin > 255) bin = 255;
            atomicAdd(&hist[bin], 1u);
        }
    }
    __syncthreads();
    if (threadIdx.x == 0) {
        u32 cum = 0; int t = 0;
        for (int bin = 255; bin >= 0; --bin) {
            cum += hist[bin];
            if (cum >= (u32)MAXDET) { t = bin; break; }
        }
        t_s = t;
    }
    __syncthreads();
    int t = t_s;
    for (int f = threadIdx.x; f < NC * MAXPC; f += blockDim.x) {
        float s = s_b[f];
        if (s > 0.f) {
            int bin = (int)(s * 256.f); if (bin > 255) bin = 255;
            if (bin >= t) {
                u32 pos = atomicAdd(&cnt_s, 1u);
                if (pos < CAPF)
                    keys[pos] = ((u64)__float_as_uint(s) << 32) | (u64)(~(u32)f);
            }
        }
    }
    __syncthreads();
    u32 g = cnt_s; if (g > (u32)CAPF) g = CAPF;
    for (int i = threadIdx.x; i < CAPF; i += blockDim.x)
        if (i >= (int)g) keys[i] = 0ull;
    __syncthreads();

    bitonic_desc(keys, CAPF);

    if (threadIdx.x < MAXDET) {
        int r = threadIdx.x;
        u64 key = keys[r];
        u32 hi = (u32)(key >> 32);
        float s = 0.f, cf = 0.f;
        float bx0 = 0.f, bx1 = 0.f, bx2 = 0.f, bx3 = 0.f;
        if (hi != 0u) {
            s = __uint_as_float(hi);
            int f = (int)(~(u32)key);
            int c = f / MAXPC, jj = f - c * MAXPC;
            const float* bsrc = bb2 + ((long)(b * NC + c) * MAXPC + jj) * 4;
            bx0 = bsrc[0]; bx1 = bsrc[1]; bx2 = bsrc[2]; bx3 = bsrc[3];
            cf = (float)c;
        }
        float* ob = out + ((long)b * MAXDET + r) * 4;
        ob[0] = bx0; ob[1] = bx1; ob[2] = bx2; ob[3] = bx3;
        out[NB * MAXDET * 4 + b * MAXDET + r] = s;
        out[NB * MAXDET * 4 + NB * MAXDET + b * MAXDET + r] = cf;
    }
    __syncthreads();
    if (threadIdx.x == 0) {
        int nv = 0;
        for (int r = 0; r < MAXDET; ++r)
            if ((u32)(keys[r] >> 32) != 0u) ++nv;
        out[NB * MAXDET * 4 + 2 * NB * MAXDET + b] = (float)nv;
    }
}

// ---------- launcher ----------

extern "C" void kernel_launch(void* const* d_in, const int* in_sizes, int n_in,
                              void* d_out, int out_size, void* d_ws, size_t ws_size,
                              hipStream_t stream) {
    // inputs: images [8,640,640,3] (unused), predictions [8,76725,84]
    const float* pred = (const float*)d_in[1];
    if (n_in >= 2 && in_sizes[0] == NB * NA * NCH) pred = (const float*)d_in[0];

    char* ws = (char*)d_ws;
    const long BCN = (long)NB * NC;                    // 640
    u64* seg   = (u64*)ws;                             // 640*256*24*8 = 31,457,280 B
    char* p    = ws + BCN * BLKX * LCAP * 8;
    u32* cntT  = (u32*)p;            p += BCN * BLKX * 4;              // 655,360 B
    float* sc2 = (float*)p;          p += BCN * MAXPC * 4;             // 256,000 B
    float* bb2 = (float*)p;                                            // 1,024,000 B

    k_scan <<<dim3(BLKX, NB), 256, 0, stream>>>((const float4*)pred, seg, cntT);
    k_nms  <<<dim3(NB * NC),  512, 0, stream>>>(pred, seg, cntT, sc2, bb2);
    k_final<<<dim3(NB),      1024, 0, stream>>>(sc2, bb2, (float*)d_out);
}